// Round 1
// baseline (799.162 us; speedup 1.0000x reference)
//
#include <hip/hip_runtime.h>

#define N_NODES 200000
#define N_EDGES 6400000
#define HID 200
#define NREP 8                    // scatter accumulators: one per XCD
#define MT 128                    // nodes per block; 1563 blocks (last has 64 real rows)
#define NBLK ((N_NODES + MT - 1) / MT)
#define ASTR 232                  // act row stride (fp16): 464 B; 2-way bank alias = free
#define WSTR 232
#define WROWS 224
#define WELEMS (WROWS * WSTR)     // per-layer elems in g_wph
#define H0ROWS 112                // half0: n-tiles 0..6
#define H1ROWS 96                 // half1: n-tiles 7..12
#define H0CH (H0ROWS * WSTR * 2 / 16)   // 3248 16-B chunks
#define H1CH (H1ROWS * WSTR * 2 / 16)   // 2784 16-B chunks

// LDS layout (bytes): act [0,59392) | buf0 [59392,111360) | buf1 [111360,155904)
//                     bias [155904,160704) | h0s [160704,161216)
// 161216 <= 163840 -> 1 block/CU (intended: intra-block pipeline replaces TLP).
#define OFF_BUF0  59392
#define OFF_BUF1  111360
#define OFF_BIAS  155904
#define OFF_H0S   160704
#define LDS_TOTAL 161216

typedef float f32x4 __attribute__((ext_vector_type(4)));
typedef _Float16 f16x8 __attribute__((ext_vector_type(8)));
typedef unsigned short u16;
typedef unsigned int u32;

__device__ __align__(16) float g_agg[NREP * N_NODES];
__device__ __align__(16) float g_xf[N_NODES];            // fp32 copy of x
__device__ __align__(16) float g_wf[6 * HID * HID];      // fp32 (VALU fallback)
__device__ __align__(16) _Float16 g_wph[6 * WELEMS];     // fp16 W^T padded [l][n][k]
__device__ int g_isbf;

__device__ __forceinline__ float bf2f(u16 u) {
  union { u32 i; float f; } v; v.i = ((u32)u) << 16; return v.f;
}
__device__ __forceinline__ u16 f2bf(float f) {  // RNE
  u32 i = __float_as_uint(f);
  return (u16)((i + 0x7FFFu + ((i >> 16) & 1u)) >> 16);
}
__device__ __forceinline__ float ldf(const void* p, int i, int isbf) {
  return isbf ? bf2f(((const u16*)p)[i]) : ((const float*)p)[i];
}
__device__ __forceinline__ void load_lds16(const void* g, void* l) {
  __builtin_amdgcn_global_load_lds(
      (const __attribute__((address_space(1))) u32*)g,
      (__attribute__((address_space(3))) u32*)l, 16, 0, 0);
}

// Raw-barrier pipeline primitives. asm volatile + "memory" clobber is a full
// compiler memory fence (orders ds_read/ds_write/global_load_lds); MFMA
// (register-only) may move but is data-dependent on ds_read results, which the
// compiler orders with its own lgkmcnt waits -> no rule-18 exposure.
#define SB() __builtin_amdgcn_sched_barrier(0)
#define WAITV(N) do { SB(); asm volatile("s_waitcnt vmcnt(" #N ")" ::: "memory"); SB(); } while (0)
#define BARRIER() do { SB(); asm volatile("s_barrier" ::: "memory"); SB(); } while (0)
#define LGKM0() do { SB(); asm volatile("s_waitcnt lgkmcnt(0)" ::: "memory"); SB(); } while (0)

// ---- rank-2 MFMA layout self-test (fp16), reference folded at compile time ----
constexpr int tf1(int m) { return (m & 3) + 1; }
constexpr int tf2(int m) { return ((m >> 2) & 3) + 2; }
constexpr int tg1(int k) { return (k & 7) + 1; }
constexpr int tg2(int k) { return ((k >> 3) & 3) + 1; }
constexpr int tu1(int k) { return ((k * 3) & 7) + 1; }
constexpr int tu2(int k) { return ((k >> 2) & 3) + 2; }
constexpr int tw1(int n) { return ((n * 5) & 7) + 1; }
constexpr int tw2(int n) { return ((n >> 2) & 3) + 1; }
constexpr int calcS(int i, int j) {
  int s = 0;
  for (int k = 0; k < 32; ++k)
    s += (i ? tg2(k) : tg1(k)) * (j ? tu2(k) : tu1(k));
  return s;
}
__device__ __forceinline__ float refD(int m, int n) {
  constexpr int S11 = calcS(0, 0), S12 = calcS(0, 1), S21 = calcS(1, 0), S22 = calcS(1, 1);
  return (float)(tf1(m) * tw1(n) * S11 + tf1(m) * tw2(n) * S12 +
                 tf2(m) * tw1(n) * S21 + tf2(m) * tw2(n) * S22);
}
__device__ int mfma_selftest(int l15, int q) {
  f16x8 av, bv;
#pragma unroll
  for (int j = 0; j < 8; ++j) {
    int k = q * 8 + j;
    av[j] = (_Float16)(float)(tf1(l15) * tg1(k) + tf2(l15) * tg2(k));
    bv[j] = (_Float16)(float)(tu1(k) * tw1(l15) + tu2(k) * tw2(l15));
  }
  f32x4 d = __builtin_amdgcn_mfma_f32_16x16x32_f16(av, bv, (f32x4){0.f, 0.f, 0.f, 0.f}, 0, 0, 0);
  bool ok0 = true, ok1 = true;
#pragma unroll
  for (int r = 0; r < 4; ++r) {
    ok0 = ok0 && (d[r] == refD(q * 4 + r, l15));
    ok1 = ok1 && (d[r] == refD(l15, q * 4 + r));
  }
  return __all(ok0) ? 0 : (__all(ok1) ? 1 : 2);
}

// ---- K0: dtype sniff ----
__global__ void sniff_kernel(const u32* __restrict__ xw) {
  int i = threadIdx.x;  // 64 threads
  u32 e = (xw[i] >> 7) & 0xFFu;
  unsigned long long b = __ballot(e >= 110u && e <= 135u);
  if (i == 0) g_isbf = (__popcll(b) >= 48) ? 1 : 0;
}

// ---- K1: zero replicas + fp32 x + both weight forms ----
__global__ void prep_kernel(const void* __restrict__ x, const void* __restrict__ w_hid) {
  int t = blockIdx.x * blockDim.x + threadIdx.x;   // 1.6M threads
  int isbf = g_isbf;
  if (t < NREP * N_NODES) g_agg[t] = 0.f;
  if (t < N_NODES) g_xf[t] = ldf(x, t, isbf);
  if (t < 6 * HID * HID) g_wf[t] = ldf(w_hid, t, isbf);
  if (t < 6 * WELEMS) {
    int l = t / WELEMS;
    int r = t - l * WELEMS;
    int n = r / WSTR;
    int k = r - n * WSTR;
    float v = 0.f;
    if (n < HID && k < HID) v = ldf(w_hid, (l * HID + k) * HID + n, isbf);
    g_wph[t] = (_Float16)v;
  }
}

// ---- K2: edge scatter-add, XCD-local atomics into the XCD's own replica ----
// Theory: device-scope (sc1) f32 atomics funnel through one memory-side RMW
// point (~18 G/s observed). Replica = physical XCC_ID => only ONE XCD ever
// touches replica r, so the no-sc1 atomic may legally execute in the local
// TCC (L2), giving 8 parallel RMW domains. Kernel-end writeback publishes.
__global__ void scatter_kernel(const int* __restrict__ ei) {
  int t = blockIdx.x * blockDim.x + threadIdx.x;   // 800K threads
  int e = t * 8;
  int xcc;
  asm volatile("s_getreg_b32 %0, hwreg(HW_REG_XCC_ID)" : "=s"(xcc));
  float* agg = g_agg + (size_t)(xcc & (NREP - 1)) * N_NODES;
  bool is64 = ((ei[1] | ei[3] | ei[5] | ei[7]) == 0);
  int s[8], d[8];
  if (is64) {
#pragma unroll
    for (int i = 0; i < 4; ++i) {
      int4 a = *(const int4*)(ei + 2 * e + 4 * i);
      int4 b = *(const int4*)(ei + 2 * N_EDGES + 2 * e + 4 * i);
      s[2 * i] = a.x; s[2 * i + 1] = a.z;
      d[2 * i] = b.x; d[2 * i + 1] = b.z;
    }
  } else {
#pragma unroll
    for (int i = 0; i < 2; ++i) {
      int4 a = *(const int4*)(ei + e + 4 * i);
      int4 b = *(const int4*)(ei + N_EDGES + e + 4 * i);
      s[4 * i] = a.x; s[4 * i + 1] = a.y; s[4 * i + 2] = a.z; s[4 * i + 3] = a.w;
      d[4 * i] = b.x; d[4 * i + 1] = b.y; d[4 * i + 2] = b.z; d[4 * i + 3] = b.w;
    }
  }
  float v[8];
#pragma unroll
  for (int i = 0; i < 8; ++i) v[i] = g_xf[s[i]];
#pragma unroll
  for (int i = 0; i < 8; ++i) {
    float* p = &agg[d[i]];
    asm volatile("global_atomic_add_f32 %0, %1, off" :: "v"(p), "v"(v[i]) : "memory");
  }
}

// ---- staging helpers (global_load_lds, 16B chunks, thread-strided) ----
// Per-wave issued-instruction counts (512 threads):
//   h0: 3248 chunks -> waves 0..2 issue 7, waves 3..7 issue 6
//   h1: 2784 chunks -> waves 0..3 issue 6, waves 4..7 issue 5
// These feed the counted-vmcnt schedule below (verified per wave class).
__device__ __forceinline__ void stage_h0(int l, int tid, _Float16* buf0) {
  const _Float16* wg = g_wph + l * WELEMS;
  for (int c = tid; c < H0CH; c += 512) load_lds16(wg + c * 8, buf0 + c * 8);
}
__device__ __forceinline__ void stage_h1(int l, int tid, _Float16* buf1) {
  const _Float16* wg = g_wph + l * WELEMS + H0ROWS * WSTR;
  for (int c = tid; c < H1CH; c += 512) load_lds16(wg + c * 8, buf1 + c * 8);
}

// ---- K3: fused MLP; MT=128, 512 thr / 8 waves, double-buffered weight
// halves, raw barriers + per-wave counted vmcnt (T3+T4) so staging of layer
// l+1 flies under the MFMA of layer l. Waves = 4 row-bands (32 rows = 2
// row-tiles each) x 2 col-groups; A-fragments cached in regs across both
// halves. ALL acc/af indices are literals (unrolled).
__global__ __launch_bounds__(512, 2) void mlp_kernel(
    const void* __restrict__ w_rel, const void* __restrict__ b_rel, const void* __restrict__ w_root,
    const void* __restrict__ w_in, const void* __restrict__ b_in,
    const void* __restrict__ b_hid, const void* __restrict__ w_out, const void* __restrict__ b_out,
    void* __restrict__ out) {
  extern __shared__ char smem[];
  _Float16* act = (_Float16*)smem;
  _Float16* buf0 = (_Float16*)(smem + OFF_BUF0);
  _Float16* buf1 = (_Float16*)(smem + OFF_BUF1);
  float* biasl = (float*)(smem + OFF_BIAS);
  float* h0s = (float*)(smem + OFF_H0S);

  const int tid = threadIdx.x;
  const int nb = blockIdx.x * MT;
  const int isbf = g_isbf;
  const int lane = tid & 63;
  const int wv = tid >> 6;          // 8 waves
  const int l15 = lane & 15;
  const int q = lane >> 4;
  const int band = wv >> 1;         // 4 bands x 32 rows
  const int cg = wv & 1;            // col group (wave-uniform)

  const int mode = mfma_selftest(l15, q);

  if (mode < 2) {
    // ---- prologue: GraphConv h0 + bias table ----
    if (tid < MT) {
      int node = nb + tid;
      float h0v = 0.f;
      if (node < N_NODES) {
        float a = 0.f;
#pragma unroll
        for (int r = 0; r < NREP; ++r) a += g_agg[(size_t)r * N_NODES + node];
        h0v = a * ldf(w_rel, 0, isbf) + ldf(b_rel, 0, isbf) +
              g_xf[node] * ldf(w_root, 0, isbf);
      }
      h0s[tid] = h0v;
    }
    for (int i = tid; i < 6 * HID; i += 512) biasl[i] = ldf(b_hid, i, isbf);
    __syncthreads();   // h0s/bias visible; compiler drains vmcnt here

    // issue layer-0 staging NOW; its latency hides under the act fill below.
    // (act-fill's w_in loads are consumed before use, so at loop entry each
    // wave's outstanding VMEM = its un-retired stage loads only.)
    stage_h0(0, tid, buf0);
    stage_h1(0, tid, buf1);

    // input layer: act[m][0..231] = relu(h0[m]*w_in + b_in), cols >=200 zero
    for (int u = tid; u < MT * 29; u += 512) {
      int m = u / 29, g = u - m * 29;
      float h0v = h0s[m];
      f16x8 pv;
#pragma unroll
      for (int jj = 0; jj < 8; ++jj) {
        int col = g * 8 + jj;
        float v = 0.f;
        if (col < HID) v = fmaxf(h0v * ldf(w_in, col, isbf) + ldf(b_in, col, isbf), 0.f);
        pv[jj] = (_Float16)v;
      }
      *(f16x8*)(act + m * ASTR + g * 8) = pv;
    }

    const _Float16* ap0 = act + (band * 32 + l15) * ASTR + q * 8;   // row-tile 0
    const _Float16* ap1 = ap0 + 16 * ASTR;                          // row-tile 1

    for (int l = 0; l < 6; ++l) {
      f32x4 acc[2][7];
#pragma unroll
      for (int rt = 0; rt < 2; ++rt)
#pragma unroll
        for (int n = 0; n < 7; ++n) acc[rt][n] = (f32x4){0.f, 0.f, 0.f, 0.f};

      // ---- wait buf0 (layer l, h0): outstanding = n_h0(l) + n_h1(l);
      // wait until only n_h1(w) remain -> this wave's h0 loads landed.
      // LGKM0 flushes prior LDS writes (epilogue / input fill) pre-barrier.
      if (wv < 4) { WAITV(6); } else { WAITV(5); }
      LGKM0();
      BARRIER();

      f16x8 af0[7], af1[7];
      __builtin_amdgcn_s_setprio(1);
      if (cg == 0) {    // tiles 0..3 -> acc[rt][0..3]
        const _Float16* bp = buf0 + l15 * WSTR + q * 8;
#pragma unroll
        for (int ks = 0; ks < 7; ++ks) {
          af0[ks] = *(const f16x8*)(ap0 + ks * 32);
          af1[ks] = *(const f16x8*)(ap1 + ks * 32);
#pragma unroll
          for (int n = 0; n < 4; ++n) {
            f16x8 b = *(const f16x8*)(bp + n * 16 * WSTR + ks * 32);
            acc[0][n] = __builtin_amdgcn_mfma_f32_16x16x32_f16(af0[ks], b, acc[0][n], 0, 0, 0);
            acc[1][n] = __builtin_amdgcn_mfma_f32_16x16x32_f16(af1[ks], b, acc[1][n], 0, 0, 0);
          }
        }
      } else {          // tiles 4..6 -> acc[rt][0..2]
        const _Float16* bp = buf0 + (4 * 16 + l15) * WSTR + q * 8;
#pragma unroll
        for (int ks = 0; ks < 7; ++ks) {
          af0[ks] = *(const f16x8*)(ap0 + ks * 32);
          af1[ks] = *(const f16x8*)(ap1 + ks * 32);
#pragma unroll
          for (int n = 0; n < 3; ++n) {
            f16x8 b = *(const f16x8*)(bp + n * 16 * WSTR + ks * 32);
            acc[0][n] = __builtin_amdgcn_mfma_f32_16x16x32_f16(af0[ks], b, acc[0][n], 0, 0, 0);
            acc[1][n] = __builtin_amdgcn_mfma_f32_16x16x32_f16(af1[ks], b, acc[1][n], 0, 0, 0);
          }
        }
      }
      __builtin_amdgcn_s_setprio(0);
      BARRIER();                      // all buf0 ds_reads retired (consumed pre-barrier)
      if (l < 5) stage_h0(l + 1, tid, buf0);     // overwrite is now safe

      // ---- wait buf1 (layer l, h1): outstanding = n_h1(l) + n_h0(l+1);
      // wait until only n_h0(w) remain. Last layer: drain.
      if (l < 5) { if (wv < 3) { WAITV(7); } else { WAITV(6); } } else { WAITV(0); }
      BARRIER();

      __builtin_amdgcn_s_setprio(1);
      if (cg == 0) {    // tiles 7..9 -> acc[rt][4..6]
        const _Float16* bp = buf1 + l15 * WSTR + q * 8;
#pragma unroll
        for (int ks = 0; ks < 7; ++ks)
#pragma unroll
          for (int n = 0; n < 3; ++n) {
            f16x8 b = *(const f16x8*)(bp + n * 16 * WSTR + ks * 32);
            acc[0][4 + n] = __builtin_amdgcn_mfma_f32_16x16x32_f16(af0[ks], b, acc[0][4 + n], 0, 0, 0);
            acc[1][4 + n] = __builtin_amdgcn_mfma_f32_16x16x32_f16(af1[ks], b, acc[1][4 + n], 0, 0, 0);
          }
      } else {          // tiles 10..12 -> acc[rt][3..5]
        const _Float16* bp = buf1 + (3 * 16 + l15) * WSTR + q * 8;
#pragma unroll
        for (int ks = 0; ks < 7; ++ks)
#pragma unroll
          for (int n = 0; n < 3; ++n) {
            f16x8 b = *(const f16x8*)(bp + n * 16 * WSTR + ks * 32);
            acc[0][3 + n] = __builtin_amdgcn_mfma_f32_16x16x32_f16(af0[ks], b, acc[0][3 + n], 0, 0, 0);
            acc[1][3 + n] = __builtin_amdgcn_mfma_f32_16x16x32_f16(af1[ks], b, acc[1][3 + n], 0, 0, 0);
          }
      }
      __builtin_amdgcn_s_setprio(0);
      BARRIER();                      // all buf1 + act reads retired
      if (l < 5) stage_h1(l + 1, tid, buf1);

      // epilogue: bias (LDS, no VMEM -> vmcnt math stays sound) + relu,
      // in-place fp16. Next-layer reads separated by the loop-top barrier.
      if (cg == 0) {    // acc[rt][0..3]->tiles 0..3, [4..6]->tiles 7..9
#pragma unroll
        for (int rt = 0; rt < 2; ++rt)
#pragma unroll
          for (int i = 0; i < 7; ++i) {
            const int gt = (i < 4) ? i : 3 + i;   // 0,1,2,3,7,8,9
            const int ctile = gt * 16;
#pragma unroll
            for (int r = 0; r < 4; ++r) {
              int rr = (mode == 0) ? (q * 4 + r) : l15;
              int cc = (mode == 0) ? l15 : (q * 4 + r);
              int row = band * 32 + rt * 16 + rr, col = ctile + cc;
              float v = acc[rt][i][r] + ((col < HID) ? biasl[l * HID + col] : 0.f);
              act[row * ASTR + col] = (_Float16)fmaxf(v, 0.f);
            }
          }
      } else {          // acc[rt][0..2]->tiles 4..6, [3..5]->tiles 10..12
#pragma unroll
        for (int rt = 0; rt < 2; ++rt)
#pragma unroll
          for (int i = 0; i < 6; ++i) {
            const int gt = (i < 3) ? 4 + i : 7 + i;  // 4,5,6,10,11,12
            const int ctile = gt * 16;
#pragma unroll
            for (int r = 0; r < 4; ++r) {
              int rr = (mode == 0) ? (q * 4 + r) : l15;
              int cc = (mode == 0) ? l15 : (q * 4 + r);
              int row = band * 32 + rt * 16 + rr, col = ctile + cc;
              float v = acc[rt][i][r] + ((col < HID) ? biasl[l * HID + col] : 0.f);
              act[row * ASTR + col] = (_Float16)fmaxf(v, 0.f);
            }
          }
      }
    }

    __syncthreads();   // flush epilogue writes; no VMEM outstanding (l=5 stages none)
    // Output layer: 8 threads/row x 25 cols, 2 passes of 64 rows
#pragma unroll
    for (int p = 0; p < 2; ++p) {
      int m = p * 64 + (tid >> 3), c = tid & 7;
      const _Float16* ar = act + m * ASTR;
      float s = 0.f;
#pragma unroll
      for (int j = c * 25; j < c * 25 + 25; ++j)
        s += (float)ar[j] * ldf(w_out, j, isbf);
      s += __shfl_down(s, 4);
      s += __shfl_down(s, 2);
      s += __shfl_down(s, 1);
      if (c == 0) {
        int node = nb + m;
        if (node < N_NODES) {
          float logit = s + ldf(b_out, 0, isbf);
          float o = 1.f / (1.f + __expf(-logit));
          if (isbf) ((u16*)out)[node] = f2bf(o);
          else ((float*)out)[node] = o;
        }
      }
    }
  } else {
    // ---- VALU fallback (defensive; 4 passes of 32 rows) ----
    float(*fA)[201] = (float(*)[201])smem;                    // 32x201 fp32
    float(*fB)[201] = (float(*)[201])(smem + 32 * 201 * 4);
    float* h0f = (float*)(smem + 64 * 201 * 4);
    for (int p = 0; p < 4; ++p) {
      __syncthreads();
      if (tid < 32) {
        int node = nb + p * 32 + tid;
        float h0v = 0.f;
        if (node < N_NODES) {
          float a = 0.f;
#pragma unroll
          for (int r = 0; r < NREP; ++r) a += g_agg[(size_t)r * N_NODES + node];
          h0v = a * ldf(w_rel, 0, isbf) + ldf(b_rel, 0, isbf) +
                g_xf[node] * ldf(w_root, 0, isbf);
        }
        h0f[tid] = h0v;
      }
      __syncthreads();
      for (int i = tid; i < 32 * HID; i += 512) {
        int mm = i / HID, ff = i - mm * HID;
        float v = h0f[mm] * ldf(w_in, ff, isbf) + ldf(b_in, ff, isbf);
        fA[mm][ff] = v > 0.f ? v : 0.f;
      }
      __syncthreads();
      const int m = tid >> 4, c = tid & 15;
      float(*ain)[201] = fA;
      float(*aout)[201] = fB;
      for (int l = 0; l < 6; ++l) {
        float acc[13];
#pragma unroll
        for (int jj = 0; jj < 13; ++jj) {
          int j = c * 13 + jj;
          acc[jj] = (j < HID) ? ldf(b_hid, l * HID + j, isbf) : 0.f;
        }
        const float* wl = g_wf + l * HID * HID;
        for (int k = 0; k < HID; ++k) {
          float a = ain[m][k];
          const float* wr = wl + k * HID;
#pragma unroll
          for (int jj = 0; jj < 13; ++jj) {
            int j = c * 13 + jj;
            if (j < HID) acc[jj] = fmaf(a, wr[j], acc[jj]);
          }
        }
        __syncthreads();
#pragma unroll
        for (int jj = 0; jj < 13; ++jj) {
          int j = c * 13 + jj;
          if (j < HID) aout[m][j] = fmaxf(acc[jj], 0.f);
        }
        float(*tsw)[201] = ain; ain = aout; aout = tsw;
        __syncthreads();
      }
      float s = 0.f;
      for (int j = c * 13; j < c * 13 + 13 && j < HID; ++j)
        s += ain[m][j] * ldf(w_out, j, isbf);
      s += __shfl_down(s, 8);
      s += __shfl_down(s, 4);
      s += __shfl_down(s, 2);
      s += __shfl_down(s, 1);
      int node = nb + p * 32 + m;
      if (c == 0 && node < N_NODES) {
        float logit = s + ldf(b_out, 0, isbf);
        float o = 1.f / (1.f + __expf(-logit));
        if (isbf) ((u16*)out)[node] = f2bf(o);
        else ((float*)out)[node] = o;
      }
    }
  }
}

extern "C" void kernel_launch(void* const* d_in, const int* in_sizes, int n_in,
                              void* d_out, int out_size, void* d_ws, size_t ws_size,
                              hipStream_t stream) {
  const void* x      = d_in[0];
  const int* ei      = (const int*)d_in[1];
  const void* w_rel  = d_in[2];
  const void* b_rel  = d_in[3];
  const void* w_root = d_in[4];
  const void* w_in   = d_in[5];
  const void* b_in   = d_in[6];
  const void* w_hid  = d_in[7];
  const void* b_hid  = d_in[8];
  const void* w_out  = d_in[9];
  const void* b_out  = d_in[10];
  (void)d_ws; (void)ws_size; (void)in_sizes; (void)n_in; (void)out_size;

  sniff_kernel<<<1, 64, 0, stream>>>((const u32*)x);
  prep_kernel<<<(NREP * N_NODES + 255) / 256, 256, 0, stream>>>(x, w_hid);
  scatter_kernel<<<N_EDGES / 8 / 256, 256, 0, stream>>>(ei);
  mlp_kernel<<<NBLK, 512, LDS_TOTAL, stream>>>(
      w_rel, b_rel, w_root, w_in, b_in, b_hid, w_out, b_out, d_out);
}

// Round 2
// 784.570 us; speedup vs baseline: 1.0186x; 1.0186x over previous
//
#include <hip/hip_runtime.h>

#define N_NODES 200000
#define N_EDGES 6400000
#define HID 200
#define NREP 8                    // scatter accumulator replicas
#define MT 64                     // nodes per block (3125 * 64 = 200000 exactly)
#define ASTR 232                  // act row stride (fp16): 464 B
#define AELEM (MT * ASTR)         // 14848 elems = 29696 B

// Packed B layout (conflict-free, sequential per-wave reads):
// g_wph[l][tile 13][ks 7][lane 64][j 8], value = W^T[n=tile*16+(lane&15)]
//                                              [k=ks*32+(lane>>4)*8+j]
#define TILE_ELEMS (7 * 512)      // 3584 elems = 7168 B per 16-col tile
#define PL_ELEMS (13 * TILE_ELEMS)// 46592 elems = 93184 B per layer
#define H0CHN (7 * TILE_ELEMS * 2 / 16)   // 3136 16-B chunks (tiles 0..6)
#define H1CHN (6 * TILE_ELEMS * 2 / 16)   // 2688 16-B chunks (tiles 7..12)

// LDS: act [0, 29696) ; wbuf [29696, 79872) ; h0s [79872, 80128)
// 80128 x 2 blocks = 160256 <= 163840 -> 2 blocks/CU.
#define LDS_WOFF 29696
#define LDS_H0S  79872
#define LDS_TOTAL 80128

typedef float f32x4 __attribute__((ext_vector_type(4)));
typedef _Float16 f16x8 __attribute__((ext_vector_type(8)));
typedef unsigned short u16;
typedef unsigned int u32;

__device__ __align__(16) float g_agg[NREP * N_NODES];
__device__ __align__(16) float g_xf[N_NODES];            // fp32 copy of x
__device__ __align__(16) float g_wf[6 * HID * HID];      // fp32 (VALU fallback)
__device__ __align__(16) _Float16 g_wph[6 * PL_ELEMS];   // fp16 packed W^T
__device__ int g_isbf;

__device__ __forceinline__ float bf2f(u16 u) {
  union { u32 i; float f; } v; v.i = ((u32)u) << 16; return v.f;
}
__device__ __forceinline__ u16 f2bf(float f) {  // RNE
  u32 i = __float_as_uint(f);
  return (u16)((i + 0x7FFFu + ((i >> 16) & 1u)) >> 16);
}
__device__ __forceinline__ float ldf(const void* p, int i, int isbf) {
  return isbf ? bf2f(((const u16*)p)[i]) : ((const float*)p)[i];
}
__device__ __forceinline__ void load_lds16(const void* g, void* l) {
  __builtin_amdgcn_global_load_lds(
      (const __attribute__((address_space(1))) u32*)g,
      (__attribute__((address_space(3))) u32*)l, 16, 0, 0);
}

// ---- rank-2 MFMA layout self-test (fp16), reference folded at compile time ----
constexpr int tf1(int m) { return (m & 3) + 1; }
constexpr int tf2(int m) { return ((m >> 2) & 3) + 2; }
constexpr int tg1(int k) { return (k & 7) + 1; }
constexpr int tg2(int k) { return ((k >> 3) & 3) + 1; }
constexpr int tu1(int k) { return ((k * 3) & 7) + 1; }
constexpr int tu2(int k) { return ((k >> 2) & 3) + 2; }
constexpr int tw1(int n) { return ((n * 5) & 7) + 1; }
constexpr int tw2(int n) { return ((n >> 2) & 3) + 1; }
constexpr int calcS(int i, int j) {
  int s = 0;
  for (int k = 0; k < 32; ++k)
    s += (i ? tg2(k) : tg1(k)) * (j ? tu2(k) : tu1(k));
  return s;
}
__device__ __forceinline__ float refD(int m, int n) {
  constexpr int S11 = calcS(0, 0), S12 = calcS(0, 1), S21 = calcS(1, 0), S22 = calcS(1, 1);
  return (float)(tf1(m) * tw1(n) * S11 + tf1(m) * tw2(n) * S12 +
                 tf2(m) * tw1(n) * S21 + tf2(m) * tw2(n) * S22);
}
__device__ int mfma_selftest(int l15, int q) {
  f16x8 av, bv;
#pragma unroll
  for (int j = 0; j < 8; ++j) {
    int k = q * 8 + j;
    av[j] = (_Float16)(float)(tf1(l15) * tg1(k) + tf2(l15) * tg2(k));
    bv[j] = (_Float16)(float)(tu1(k) * tw1(l15) + tu2(k) * tw2(l15));
  }
  f32x4 d = __builtin_amdgcn_mfma_f32_16x16x32_f16(av, bv, (f32x4){0.f, 0.f, 0.f, 0.f}, 0, 0, 0);
  bool ok0 = true, ok1 = true;
#pragma unroll
  for (int r = 0; r < 4; ++r) {
    ok0 = ok0 && (d[r] == refD(q * 4 + r, l15));
    ok1 = ok1 && (d[r] == refD(l15, q * 4 + r));
  }
  return __all(ok0) ? 0 : (__all(ok1) ? 1 : 2);
}

// ---- K0: dtype sniff ----
__global__ void sniff_kernel(const u32* __restrict__ xw) {
  int i = threadIdx.x;  // 64 threads
  u32 e = (xw[i] >> 7) & 0xFFu;
  unsigned long long b = __ballot(e >= 110u && e <= 135u);
  if (i == 0) g_isbf = (__popcll(b) >= 48) ? 1 : 0;
}

// ---- K1: zero replicas + fp32 x + both weight forms ----
__global__ void prep_kernel(const void* __restrict__ x, const void* __restrict__ w_hid) {
  int t = blockIdx.x * blockDim.x + threadIdx.x;   // 1.6M threads
  int isbf = g_isbf;
  if (t < NREP * N_NODES) g_agg[t] = 0.f;
  if (t < N_NODES) g_xf[t] = ldf(x, t, isbf);
  if (t < 6 * HID * HID) g_wf[t] = ldf(w_hid, t, isbf);
  if (t < 6 * PL_ELEMS) {
    int l = t / PL_ELEMS;
    int r = t - l * PL_ELEMS;
    int tile = r / TILE_ELEMS;
    int r2 = r - tile * TILE_ELEMS;
    int ks = r2 >> 9;              // 512 elems per (tile,ks) subtile
    int r3 = r2 & 511;
    int ln = r3 >> 3;              // lane 0..63
    int j  = r3 & 7;
    int q  = ln >> 4;
    int l15 = ln & 15;
    int n = tile * 16 + l15;
    int k = ks * 32 + q * 8 + j;
    float v = (n < HID && k < HID) ? ldf(w_hid, (l * HID + k) * HID + n, isbf) : 0.f;
    g_wph[t] = (_Float16)v;
  }
}

// ---- K2: edge scatter-add; 8 edges/thread, XCD-local replica ----
__global__ void scatter_kernel(const int* __restrict__ ei) {
  int t = blockIdx.x * blockDim.x + threadIdx.x;   // 800K threads
  int e = t * 8;
  int xcc;
  asm volatile("s_getreg_b32 %0, hwreg(HW_REG_XCC_ID)" : "=s"(xcc));
  float* agg = g_agg + (size_t)(xcc & (NREP - 1)) * N_NODES;
  bool is64 = ((ei[1] | ei[3] | ei[5] | ei[7]) == 0);
  int s[8], d[8];
  if (is64) {
#pragma unroll
    for (int i = 0; i < 4; ++i) {
      int4 a = *(const int4*)(ei + 2 * e + 4 * i);
      int4 b = *(const int4*)(ei + 2 * N_EDGES + 2 * e + 4 * i);
      s[2 * i] = a.x; s[2 * i + 1] = a.z;
      d[2 * i] = b.x; d[2 * i + 1] = b.z;
    }
  } else {
#pragma unroll
    for (int i = 0; i < 2; ++i) {
      int4 a = *(const int4*)(ei + e + 4 * i);
      int4 b = *(const int4*)(ei + N_EDGES + e + 4 * i);
      s[4 * i] = a.x; s[4 * i + 1] = a.y; s[4 * i + 2] = a.z; s[4 * i + 3] = a.w;
      d[4 * i] = b.x; d[4 * i + 1] = b.y; d[4 * i + 2] = b.z; d[4 * i + 3] = b.w;
    }
  }
  float v[8];
#pragma unroll
  for (int i = 0; i < 8; ++i) v[i] = g_xf[s[i]];
#pragma unroll
  for (int i = 0; i < 8; ++i) {
    float* p = &agg[d[i]];
    asm volatile("global_atomic_add_f32 %0, %1, off" :: "v"(p), "v"(v[i]) : "memory");
  }
}

// ---- K3: fused MLP; MT=64, 512 thr / 8 waves, 2 blocks/CU (R0 skeleton).
// Changes vs R0: (1) packed B layout -> each wave's B-frag reads are 1024
// CONSECUTIVE bytes (zero bank conflicts, imm-offset addressing, no addr
// VALU); (2) A-fragments register-cached across both weight halves (A LDS
// reads halved). ALL acc/af indices are literals.
__global__ __launch_bounds__(512, 4) void mlp_kernel(
    const void* __restrict__ w_rel, const void* __restrict__ b_rel, const void* __restrict__ w_root,
    const void* __restrict__ w_in, const void* __restrict__ b_in,
    const void* __restrict__ b_hid, const void* __restrict__ w_out, const void* __restrict__ b_out,
    void* __restrict__ out) {
  extern __shared__ char smem[];
  _Float16* act = (_Float16*)smem;
  _Float16* wbuf = (_Float16*)(smem + LDS_WOFF);
  float* h0s = (float*)(smem + LDS_H0S);

  const int tid = threadIdx.x;
  const int nb = blockIdx.x * MT;
  const int isbf = g_isbf;
  const int lane = tid & 63;
  const int wv = tid >> 6;          // 8 waves
  const int l15 = lane & 15;
  const int q = lane >> 4;
  const int band = wv >> 1;         // 4 bands x 16 rows
  const int cg = wv & 1;            // col group (wave-uniform)

  const int mode = mfma_selftest(l15, q);

  // GraphConv h0 (8 replicas summed)
  if (tid < MT) {
    int node = nb + tid;
    float a = 0.f;
#pragma unroll
    for (int r = 0; r < NREP; ++r) a += g_agg[(size_t)r * N_NODES + node];
    h0s[tid] = a * ldf(w_rel, 0, isbf) + ldf(b_rel, 0, isbf) +
               g_xf[node] * ldf(w_root, 0, isbf);
  }
  __syncthreads();

  if (mode < 2) {
    // Input layer (vectorized): act[m][0..231], cols >= HID zeroed
    for (int u = tid; u < MT * 29; u += 512) {
      int m = u / 29, g = u - m * 29;
      float h0v = h0s[m];
      f16x8 pv;
#pragma unroll
      for (int jj = 0; jj < 8; ++jj) {
        int col = g * 8 + jj;
        float v = 0.f;
        if (col < HID) v = fmaxf(h0v * ldf(w_in, col, isbf) + ldf(b_in, col, isbf), 0.f);
        pv[jj] = (_Float16)v;
      }
      *(f16x8*)(act + m * ASTR + g * 8) = pv;
    }

    const _Float16* ap = act + (band * 16 + l15) * ASTR + q * 8;
    const _Float16* bp = wbuf + lane * 8;   // all B reads: bp + imm offset

    for (int l = 0; l < 6; ++l) {
      f32x4 acc[7];
#pragma unroll
      for (int n = 0; n < 7; ++n) acc[n] = (f32x4){0.f, 0.f, 0.f, 0.f};

      // ---- half 0: tiles 0..6 at buffer slots 0..6 ----
      __syncthreads();  // act stable, prior-layer wbuf reads done
      {
        const _Float16* wg = g_wph + l * PL_ELEMS;
        for (int c = tid; c < H0CHN; c += 512) load_lds16(wg + c * 8, wbuf + c * 8);
      }
      __syncthreads();  // drain staging
      f16x8 af[7];      // A-fragments cached across both halves
      if (cg == 0) {    // slots 0..3 -> acc[0..3]
#pragma unroll
        for (int ks = 0; ks < 7; ++ks) {
          af[ks] = *(const f16x8*)(ap + ks * 32);
#pragma unroll
          for (int n = 0; n < 4; ++n) {
            f16x8 b = *(const f16x8*)(bp + (n * 7 + ks) * 512);
            acc[n] = __builtin_amdgcn_mfma_f32_16x16x32_f16(af[ks], b, acc[n], 0, 0, 0);
          }
        }
      } else {          // slots 4..6 -> acc[0..2]
#pragma unroll
        for (int ks = 0; ks < 7; ++ks) {
          af[ks] = *(const f16x8*)(ap + ks * 32);
#pragma unroll
          for (int n = 0; n < 3; ++n) {
            f16x8 b = *(const f16x8*)(bp + ((4 + n) * 7 + ks) * 512);
            acc[n] = __builtin_amdgcn_mfma_f32_16x16x32_f16(af[ks], b, acc[n], 0, 0, 0);
          }
        }
      }

      // ---- half 1: tiles 7..12 at buffer slots 0..5 ----
      __syncthreads();  // all half-0 B reads done before overwrite
      {
        const _Float16* wg = g_wph + l * PL_ELEMS + 7 * TILE_ELEMS;
        for (int c = tid; c < H1CHN; c += 512) load_lds16(wg + c * 8, wbuf + c * 8);
      }
      __syncthreads();  // drain staging
      if (cg == 0) {    // slots 0..2 = tiles 7..9 -> acc[4..6]
#pragma unroll
        for (int ks = 0; ks < 7; ++ks)
#pragma unroll
          for (int n = 0; n < 3; ++n) {
            f16x8 b = *(const f16x8*)(bp + (n * 7 + ks) * 512);
            acc[4 + n] = __builtin_amdgcn_mfma_f32_16x16x32_f16(af[ks], b, acc[4 + n], 0, 0, 0);
          }
      } else {          // slots 3..5 = tiles 10..12 -> acc[3..5]
#pragma unroll
        for (int ks = 0; ks < 7; ++ks)
#pragma unroll
          for (int n = 0; n < 3; ++n) {
            f16x8 b = *(const f16x8*)(bp + ((3 + n) * 7 + ks) * 512);
            acc[3 + n] = __builtin_amdgcn_mfma_f32_16x16x32_f16(af[ks], b, acc[3 + n], 0, 0, 0);
          }
      }
      __syncthreads();  // all act/wbuf reads done before in-place act writes

      // epilogue: bias + relu, in-place fp16 (all acc indices literal)
      if (cg == 0) {    // acc[0..3]->tiles 0..3, acc[4..6]->tiles 7..9
#pragma unroll
        for (int i = 0; i < 7; ++i) {
          const int gt = (i < 4) ? i : 3 + i;   // 0,1,2,3,7,8,9
          const int ctile = gt * 16;
#pragma unroll
          for (int r = 0; r < 4; ++r) {
            int rr = (mode == 0) ? (q * 4 + r) : l15;
            int cc = (mode == 0) ? l15 : (q * 4 + r);
            int row = band * 16 + rr, col = ctile + cc;
            float v = acc[i][r] + ((col < HID) ? ldf(b_hid, l * HID + col, isbf) : 0.f);
            act[row * ASTR + col] = (_Float16)fmaxf(v, 0.f);
          }
        }
      } else {          // acc[0..2]->tiles 4..6, acc[3..5]->tiles 10..12
#pragma unroll
        for (int i = 0; i < 6; ++i) {
          const int gt = (i < 3) ? 4 + i : 7 + i;  // 4,5,6,10,11,12
          const int ctile = gt * 16;
#pragma unroll
          for (int r = 0; r < 4; ++r) {
            int rr = (mode == 0) ? (q * 4 + r) : l15;
            int cc = (mode == 0) ? l15 : (q * 4 + r);
            int row = band * 16 + rr, col = ctile + cc;
            float v = acc[i][r] + ((col < HID) ? ldf(b_hid, l * HID + col, isbf) : 0.f);
            act[row * ASTR + col] = (_Float16)fmaxf(v, 0.f);
          }
        }
      }
    }

    __syncthreads();
    // Output layer: 8 threads/row x 25 cols
    {
      int m = tid >> 3, c = tid & 7;
      const _Float16* ar = act + m * ASTR;
      float s = 0.f;
#pragma unroll
      for (int j = c * 25; j < c * 25 + 25; ++j)
        s += (float)ar[j] * ldf(w_out, j, isbf);
      s += __shfl_down(s, 4);
      s += __shfl_down(s, 2);
      s += __shfl_down(s, 1);
      if (c == 0) {
        float logit = s + ldf(b_out, 0, isbf);
        float o = 1.f / (1.f + __expf(-logit));
        if (isbf) ((u16*)out)[nb + m] = f2bf(o);
        else ((float*)out)[nb + m] = o;
      }
    }
  } else {
    // ---- VALU fallback (defensive; 2 passes of 32 rows) ----
    float(*fA)[201] = (float(*)[201])smem;                    // 32x201 fp32
    float(*fB)[201] = (float(*)[201])(smem + 32 * 201 * 4);
    float* h0f = (float*)(smem + 64 * 201 * 4);
    for (int p = 0; p < 2; ++p) {
      __syncthreads();
      if (tid < 32) {
        int node = nb + p * 32 + tid;
        float a = 0.f;
#pragma unroll
        for (int r = 0; r < NREP; ++r) a += g_agg[(size_t)r * N_NODES + node];
        h0f[tid] = a * ldf(w_rel, 0, isbf) + ldf(b_rel, 0, isbf) +
                   g_xf[node] * ldf(w_root, 0, isbf);
      }
      __syncthreads();
      for (int i = tid; i < 32 * HID; i += 512) {
        int mm = i / HID, ff = i - mm * HID;
        float v = h0f[mm] * ldf(w_in, ff, isbf) + ldf(b_in, ff, isbf);
        fA[mm][ff] = v > 0.f ? v : 0.f;
      }
      __syncthreads();
      const int m = tid >> 4, c = tid & 15;
      float(*ain)[201] = fA;
      float(*aout)[201] = fB;
      for (int l = 0; l < 6; ++l) {
        float acc[13];
#pragma unroll
        for (int jj = 0; jj < 13; ++jj) {
          int j = c * 13 + jj;
          acc[jj] = (j < HID) ? ldf(b_hid, l * HID + j, isbf) : 0.f;
        }
        const float* wl = g_wf + l * HID * HID;
        for (int k = 0; k < HID; ++k) {
          float a = ain[m][k];
          const float* wr = wl + k * HID;
#pragma unroll
          for (int jj = 0; jj < 13; ++jj) {
            int j = c * 13 + jj;
            if (j < HID) acc[jj] = fmaf(a, wr[j], acc[jj]);
          }
        }
        __syncthreads();
#pragma unroll
        for (int jj = 0; jj < 13; ++jj) {
          int j = c * 13 + jj;
          if (j < HID) aout[m][j] = fmaxf(acc[jj], 0.f);
        }
        float(*tsw)[201] = ain; ain = aout; aout = tsw;
        __syncthreads();
      }
      float s = 0.f;
      for (int j = c * 13; j < c * 13 + 13 && j < HID; ++j)
        s += ain[m][j] * ldf(w_out, j, isbf);
      s += __shfl_down(s, 8);
      s += __shfl_down(s, 4);
      s += __shfl_down(s, 2);
      s += __shfl_down(s, 1);
      int node = nb + p * 32 + m;
      if (c == 0) {
        float logit = s + ldf(b_out, 0, isbf);
        float o = 1.f / (1.f + __expf(-logit));
        if (isbf) ((u16*)out)[node] = f2bf(o);
        else ((float*)out)[node] = o;
      }
    }
  }
}

extern "C" void kernel_launch(void* const* d_in, const int* in_sizes, int n_in,
                              void* d_out, int out_size, void* d_ws, size_t ws_size,
                              hipStream_t stream) {
  const void* x      = d_in[0];
  const int* ei      = (const int*)d_in[1];
  const void* w_rel  = d_in[2];
  const void* b_rel  = d_in[3];
  const void* w_root = d_in[4];
  const void* w_in   = d_in[5];
  const void* b_in   = d_in[6];
  const void* w_hid  = d_in[7];
  const void* b_hid  = d_in[8];
  const void* w_out  = d_in[9];
  const void* b_out  = d_in[10];
  (void)d_ws; (void)ws_size; (void)in_sizes; (void)n_in; (void)out_size;

  sniff_kernel<<<1, 64, 0, stream>>>((const u32*)x);
  prep_kernel<<<(NREP * N_NODES + 255) / 256, 256, 0, stream>>>(x, w_hid);
  scatter_kernel<<<N_EDGES / 8 / 256, 256, 0, stream>>>(ei);
  mlp_kernel<<<N_NODES / MT, 512, LDS_TOTAL, stream>>>(
      w_rel, b_rel, w_root, w_in, b_in, b_hid, w_out, b_out, d_out);
}